// Round 13
// baseline (113.309 us; speedup 1.0000x reference)
//
#include <hip/hip_runtime.h>
#include <hip/hip_bf16.h>

typedef __attribute__((ext_vector_type(8)))  float f8;
typedef __attribute__((ext_vector_type(16))) float f32x16;
typedef __attribute__((ext_vector_type(8)))  short bf8;

__device__ __forceinline__ short f2bf(float f) {
    unsigned u = __builtin_bit_cast(unsigned, f);
    u += 0x7fff + ((u >> 16) & 1);          // round-to-nearest-even
    return (short)(u >> 16);
}

__device__ __forceinline__ unsigned cvt_pk_bf16(float a, float b) {
    unsigned r;
    asm("v_cvt_pk_bf16_f32 %0, %1, %2" : "=v"(r) : "v"(a), "v"(b));
    return r;                                // lo = bf16(a), hi = bf16(b)
}

// ---------------------------------------------------------------------------
// Prep (validated rounds 7/11/12, absmax 0.5): fused B-matrix [256][128]
// packed as 32x32x16 MFMA B-fragments. f = kt*4+nt, kt=0..15, nt=0..3:
//   pre[(f*64 + lane)*8 + j] = Bmat[kt*16 + (lane>>5)*8 + j][nt*32 + (lane&31)]
//   Bmat[k][n] = k<128 ? U_w[n][k]
//                      : A_w[n][k-128]*dw[k-128]/dw[n] + (n==k-128)*(0.05-rs[n])
// ---------------------------------------------------------------------------
__global__ void nemon_prep(const float* __restrict__ Uw,
                           const float* __restrict__ Aw,
                           const float* __restrict__ dvec,
                           short* __restrict__ pre)
{
    __shared__ float rs[128], dwv[128];
    const int tid = threadIdx.x;
    if (tid < 128) {
        float s = 0.f;
        #pragma unroll 8
        for (int k = 0; k < 128; ++k) s += fabsf(Aw[tid * 128 + k]);
        rs[tid]  = s;
        dwv[tid] = expf(dvec[tid]);
    }
    __syncthreads();
    #pragma unroll
    for (int half = 0; half < 2; ++half) {
        const int e    = blockIdx.x * 512 + half * 256 + tid;
        const int j    = e & 7;
        const int lane = (e >> 3) & 63;
        const int f    = e >> 9;          // 0..63
        const int nt   = f & 3;
        const int kt   = f >> 2;          // 0..15
        const int k    = kt * 16 + (lane >> 5) * 8 + j;
        const int n    = nt * 32 + (lane & 31);
        float v;
        if (k < 128) {
            v = Uw[n * 128 + k];
        } else {
            const int k2 = k - 128;
            v = Aw[n * 128 + k2] * (dwv[k2] / dwv[n]);
            if (n == k2) v += 0.05f - rs[n];
        }
        pre[e] = f2bf(v);
    }
}

// ---------------------------------------------------------------------------
// Main v10: PURE STREAMING regime. No LDS, no barriers, 1 tile (32 rows)
// per wave, 2048 small desynchronized blocks (up to 8/CU), VGPR capped at
// 128 -> ~16 waves/CU hiding latency by TLP alone (m146-streaming recipe).
// B-fragments are read per-use from global `pre` (64 KB, L1/L2-hot;
// 16 B/lane consecutive = one dense 1 KB burst per fragment).
// fp32->bf16 via v_cvt_pk_bf16_f32 (2 elems/inst). Dense per-wave stores
// (32x32 C layout, m74/m101: col=lane&31, row=(reg&3)+8*(reg>>2)+4*hi).
// ---------------------------------------------------------------------------
__global__ __launch_bounds__(256, 4) void nemon_main(
    const float* __restrict__ x,
    const float* __restrict__ z,
    const float* __restrict__ Ub,
    const short* __restrict__ pre,
    float* __restrict__ out)
{
    const int tid  = threadIdx.x;
    const int wave = tid >> 6;
    const int lane = tid & 63;
    const int lo   = lane & 31;           // A row / C col (within 32-tiles)
    const int hi   = lane >> 5;           // k-half selector

    const long R = ((long)blockIdx.x * 4 + wave) * 32;   // this wave's 32 rows

    f32x16 acc[4];
    #pragma unroll
    for (int nt = 0; nt < 4; ++nt) {
        const float b = Ub[nt * 32 + lo];
        #pragma unroll
        for (int r = 0; r < 16; ++r) acc[nt][r] = b;
    }

    const float* xr = x + (R + lo) * 128 + hi * 8;
    const float* zr = z + (R + lo) * 128 + hi * 8;

    #pragma unroll
    for (int kt = 0; kt < 16; ++kt) {
        const float* src = (kt < 8) ? (xr + kt * 16) : (zr + (kt - 8) * 16);
        f8 v = *(const f8*)src;           // 32 B/lane, coalesced
        union { bf8 b; unsigned u[4]; } a;
        a.u[0] = cvt_pk_bf16(v[0], v[1]);
        a.u[1] = cvt_pk_bf16(v[2], v[3]);
        a.u[2] = cvt_pk_bf16(v[4], v[5]);
        a.u[3] = cvt_pk_bf16(v[6], v[7]);
        #pragma unroll
        for (int nt = 0; nt < 4; ++nt) {
            bf8 b = *(const bf8*)(pre + (long)((kt * 4 + nt) * 64 + lane) * 8);
            acc[nt] = __builtin_amdgcn_mfma_f32_32x32x16_bf16(a.b, b, acc[nt], 0, 0, 0);
        }
    }

    // stores: 2 x 128 B dense segments per instruction (WRITE_SIZE-exact)
    float* ob = out + R * 128;
    #pragma unroll
    for (int reg = 0; reg < 16; ++reg) {
        const int rowA = (reg & 3) + 8 * (reg >> 2) + 4 * hi;
        #pragma unroll
        for (int nt = 0; nt < 4; ++nt)
            ob[rowA * 128 + nt * 32 + lo] = acc[nt][reg];
    }
}

extern "C" void kernel_launch(void* const* d_in, const int* in_sizes, int n_in,
                              void* d_out, int out_size, void* d_ws, size_t ws_size,
                              hipStream_t stream) {
    const float* x  = (const float*)d_in[0];
    const float* z  = (const float*)d_in[1];
    const float* Uw = (const float*)d_in[2];
    const float* Ub = (const float*)d_in[3];
    const float* Aw = (const float*)d_in[4];
    const float* dv = (const float*)d_in[5];
    float* out = (float*)d_out;
    short* pre = (short*)d_ws;            // 64 KB prepacked weights

    const int B = in_sizes[0] / 128;      // 262144 rows
    nemon_prep<<<64, 256, 0, stream>>>(Uw, Aw, dv, pre);
    nemon_main<<<B / 128, 256, 0, stream>>>(x, z, Ub, pre, out);
}

// Round 14
// 96.978 us; speedup vs baseline: 1.1684x; 1.1684x over previous
//
#include <hip/hip_runtime.h>
#include <hip/hip_bf16.h>

typedef __attribute__((ext_vector_type(8)))  float f8;
typedef __attribute__((ext_vector_type(16))) float f32x16;
typedef __attribute__((ext_vector_type(8)))  short bf8;

__device__ __forceinline__ short f2bf(float f) {
    unsigned u = __builtin_bit_cast(unsigned, f);
    u += 0x7fff + ((u >> 16) & 1);          // round-to-nearest-even
    return (short)(u >> 16);
}

__device__ __forceinline__ unsigned cvt_pk_bf16(float a, float b) {
    unsigned r;
    asm("v_cvt_pk_bf16_f32 %0, %1, %2" : "=v"(r) : "v"(a), "v"(b));
    return r;                                // lo = bf16(a), hi = bf16(b)
}

// ---------------------------------------------------------------------------
// Prep (validated rounds 7/11/12/13, absmax 0.5): fused B-matrix [256][128]
// packed as 32x32x16 MFMA B-fragments. f = kt*4+nt, kt=0..15, nt=0..3:
//   pre[(f*64 + lane)*8 + j] = Bmat[kt*16 + (lane>>5)*8 + j][nt*32 + (lane&31)]
//   Bmat[k][n] = k<128 ? U_w[n][k]
//                      : A_w[n][k-128]*dw[k-128]/dw[n] + (n==k-128)*(0.05-rs[n])
// ---------------------------------------------------------------------------
__global__ void nemon_prep(const float* __restrict__ Uw,
                           const float* __restrict__ Aw,
                           const float* __restrict__ dvec,
                           short* __restrict__ pre)
{
    __shared__ float rs[128], dwv[128];
    const int tid = threadIdx.x;
    if (tid < 128) {
        float s = 0.f;
        #pragma unroll 8
        for (int k = 0; k < 128; ++k) s += fabsf(Aw[tid * 128 + k]);
        rs[tid]  = s;
        dwv[tid] = expf(dvec[tid]);
    }
    __syncthreads();
    #pragma unroll
    for (int half = 0; half < 2; ++half) {
        const int e    = blockIdx.x * 512 + half * 256 + tid;
        const int j    = e & 7;
        const int lane = (e >> 3) & 63;
        const int f    = e >> 9;          // 0..63
        const int nt   = f & 3;
        const int kt   = f >> 2;          // 0..15
        const int k    = kt * 16 + (lane >> 5) * 8 + j;
        const int n    = nt * 32 + (lane & 31);
        float v;
        if (k < 128) {
            v = Uw[n * 128 + k];
        } else {
            const int k2 = k - 128;
            v = Aw[n * 128 + k2] * (dwv[k2] / dwv[n]);
            if (n == k2) v += 0.05f - rs[n];
        }
        pre[e] = f2bf(v);
    }
}

// ---------------------------------------------------------------------------
// Main v11 = v9 pipeline + backfill grid + packed converts.
// 256 thr = 4 waves; weights in 64 KB LDS (one barrier). Each wave: 2
// grid-strided 32-row tiles; next tile's x refills right after the x-phase
// consumes bufA (z likewise), so ~4-8 KB/wave of loads stay in flight
// through MFMA+store with no barrier to drain them. 1024 blocks vs 512
// resident -> queued blocks rebalance CU placement skew (v9's measured
// 10.7% avg occupancy) and desynchronize waves. launch_bounds(256,1):
// no spill at ~224 VGPR. Dense 2x128B stores (32x32 C layout, m74/m101).
// ---------------------------------------------------------------------------
__global__ __launch_bounds__(256, 1) void nemon_main(
    const float* __restrict__ x,
    const float* __restrict__ z,
    const float* __restrict__ Ub,
    const short* __restrict__ pre,
    float* __restrict__ out)
{
    __shared__ short W[32768];            // 64 KB B-fragments = 4096 int4
    const int tid = threadIdx.x;

    {   // stage weights, linear: 4096 int4 / 256 thr = 16 each
        const int4* src = (const int4*)pre;
        int4*       dst = (int4*)W;
        #pragma unroll
        for (int i = 0; i < 16; ++i) dst[tid + 256 * i] = src[tid + 256 * i];
    }
    __syncthreads();                      // the only barrier

    const int wave = tid >> 6;
    const int lane = tid & 63;
    const int lo   = lane & 31;           // A row / C col (within 32-tiles)
    const int hi   = lane >> 5;           // k-half selector

    const int  wgid = blockIdx.x * 4 + wave;     // 0..4095
    const long TROW = (long)4096 * 32;           // rows between a wave's 2 tiles

    float ubv[4];
    #pragma unroll
    for (int nt = 0; nt < 4; ++nt) ubv[nt] = Ub[nt * 32 + lo];

    const long   R0 = (long)wgid * 32;
    const float* xr = x + (R0 + lo) * 128 + hi * 8;
    const float* zr = z + (R0 + lo) * 128 + hi * 8;

    // prologue: tile-0 x and z issued (128 VGPR in flight)
    f8 bufA[8], bufB[8];
    #pragma unroll
    for (int i = 0; i < 8; ++i) bufA[i] = *(const f8*)(xr + i * 16);
    #pragma unroll
    for (int i = 0; i < 8; ++i) bufB[i] = *(const f8*)(zr + i * 16);

    #pragma unroll
    for (int it = 0; it < 2; ++it) {
        f32x16 acc[4];
        #pragma unroll
        for (int nt = 0; nt < 4; ++nt) {
            #pragma unroll
            for (int r = 0; r < 16; ++r) acc[nt][r] = ubv[nt];
        }

        // x-phase: k-steps 0..7 (bufA[kt] covers k = kt*16 + hi*8 + j)
        #pragma unroll
        for (int kt = 0; kt < 8; ++kt) {
            union { bf8 b; unsigned u[4]; } a;
            a.u[0] = cvt_pk_bf16(bufA[kt][0], bufA[kt][1]);
            a.u[1] = cvt_pk_bf16(bufA[kt][2], bufA[kt][3]);
            a.u[2] = cvt_pk_bf16(bufA[kt][4], bufA[kt][5]);
            a.u[3] = cvt_pk_bf16(bufA[kt][6], bufA[kt][7]);
            #pragma unroll
            for (int nt = 0; nt < 4; ++nt) {
                bf8 b = *(const bf8*)&W[((kt * 4 + nt) * 64 + lane) * 8];
                acc[nt] = __builtin_amdgcn_mfma_f32_32x32x16_bf16(a.b, b, acc[nt], 0, 0, 0);
            }
        }
        // bufA dead -> issue tile-1's x (in flight through z-phase + store)
        if (it == 0) {
            const float* nx = xr + TROW * 128;
            #pragma unroll
            for (int i = 0; i < 8; ++i) bufA[i] = *(const f8*)(nx + i * 16);
        }

        // z-phase: k-steps 8..15
        #pragma unroll
        for (int kt = 0; kt < 8; ++kt) {
            union { bf8 b; unsigned u[4]; } a;
            a.u[0] = cvt_pk_bf16(bufB[kt][0], bufB[kt][1]);
            a.u[1] = cvt_pk_bf16(bufB[kt][2], bufB[kt][3]);
            a.u[2] = cvt_pk_bf16(bufB[kt][4], bufB[kt][5]);
            a.u[3] = cvt_pk_bf16(bufB[kt][6], bufB[kt][7]);
            #pragma unroll
            for (int nt = 0; nt < 4; ++nt) {
                bf8 b = *(const bf8*)&W[(((kt + 8) * 4 + nt) * 64 + lane) * 8];
                acc[nt] = __builtin_amdgcn_mfma_f32_32x32x16_bf16(a.b, b, acc[nt], 0, 0, 0);
            }
        }
        // bufB dead -> issue tile-1's z (in flight through store + next x-phase)
        if (it == 0) {
            const float* nz = zr + TROW * 128;
            #pragma unroll
            for (int i = 0; i < 8; ++i) bufB[i] = *(const f8*)(nz + i * 16);
        }

        // stores: C layout col=lane&31, row=(reg&3)+8*(reg>>2)+4*hi
        // (2 x 128B dense segments per instruction; WRITE_SIZE-exact)
        float* ob = out + (R0 + (long)it * TROW) * 128;
        #pragma unroll
        for (int reg = 0; reg < 16; ++reg) {
            const int rowA = (reg & 3) + 8 * (reg >> 2) + 4 * hi;
            #pragma unroll
            for (int nt = 0; nt < 4; ++nt)
                ob[rowA * 128 + nt * 32 + lo] = acc[nt][reg];
        }
    }
}

extern "C" void kernel_launch(void* const* d_in, const int* in_sizes, int n_in,
                              void* d_out, int out_size, void* d_ws, size_t ws_size,
                              hipStream_t stream) {
    const float* x  = (const float*)d_in[0];
    const float* z  = (const float*)d_in[1];
    const float* Uw = (const float*)d_in[2];
    const float* Ub = (const float*)d_in[3];
    const float* Aw = (const float*)d_in[4];
    const float* dv = (const float*)d_in[5];
    float* out = (float*)d_out;
    short* pre = (short*)d_ws;            // 64 KB prepacked weights

    nemon_prep<<<64, 256, 0, stream>>>(Uw, Aw, dv, pre);
    nemon_main<<<1024, 256, 0, stream>>>(x, z, Ub, pre, out);
}